// Round 1
// baseline (55.427 us; speedup 1.0000x reference)
//
#include <hip/hip_runtime.h>
#include <hip/hip_bf16.h>

static constexpr int BLOCK     = 256;
static constexpr int GRID_MAIN = 2048;
static constexpr int GRID_FIX  = 32;

__device__ __forceinline__ float patch_nan(float x) {
    return (x != x) ? 1e-6f : x;
}

// non-target term: -(1-alpha) * p^2 * ln(1-p)   (alpha = 0.25)
__device__ __forceinline__ float neg_term(float x) {
    return -0.75f * x * x * __logf(1.0f - x);
}

// target term: -alpha * (1-p)^2 * ln(p)
__device__ __forceinline__ float pos_term(float x) {
    float om = 1.0f - x;
    return -0.25f * om * om * __logf(x);
}

// Block-wide sum; result valid in thread 0 only.
__device__ __forceinline__ float block_reduce_sum(float v) {
    #pragma unroll
    for (int off = 32; off > 0; off >>= 1)
        v += __shfl_down(v, off, 64);
    __shared__ float smem[BLOCK / 64];
    const int lane = threadIdx.x & 63;
    const int wid  = threadIdx.x >> 6;
    if (lane == 0) smem[wid] = v;
    __syncthreads();
    float r = 0.0f;
    if (threadIdx.x == 0) {
        #pragma unroll
        for (int i = 0; i < BLOCK / 64; ++i) r += smem[i];
    }
    return r;
}

// Pass 1: treat EVERY element as non-target; coalesced float4 stream.
__global__ void __launch_bounds__(BLOCK)
focal_main(const float4* __restrict__ p4, float* __restrict__ partials, int n4) {
    float acc = 0.0f;
    const int stride = gridDim.x * blockDim.x;
    for (int i = blockIdx.x * blockDim.x + threadIdx.x; i < n4; i += stride) {
        float4 v = p4[i];
        acc += neg_term(patch_nan(v.x));
        acc += neg_term(patch_nan(v.y));
        acc += neg_term(patch_nan(v.z));
        acc += neg_term(patch_nan(v.w));
    }
    float r = block_reduce_sum(acc);
    if (threadIdx.x == 0) partials[blockIdx.x] = r;
}

// Pass 2: correct the one target element per row: add (pos - neg) there.
__global__ void __launch_bounds__(BLOCK)
focal_fix(const float* __restrict__ p, const int* __restrict__ classes,
          float* __restrict__ partials, int B, int C) {
    float acc = 0.0f;
    const int stride = gridDim.x * blockDim.x;
    for (int b = blockIdx.x * blockDim.x + threadIdx.x; b < B; b += stride) {
        int c = classes[b];
        float x = patch_nan(p[(long long)b * C + c]);
        acc += pos_term(x) - neg_term(x);
    }
    float r = block_reduce_sum(acc);
    if (threadIdx.x == 0) partials[blockIdx.x] = r;
}

// Pass 3: deterministic final reduction of all partials, scale by 1/B.
__global__ void __launch_bounds__(BLOCK)
focal_final(const float* __restrict__ partials, int n,
            float* __restrict__ out, float invB) {
    float acc = 0.0f;
    for (int i = threadIdx.x; i < n; i += blockDim.x) acc += partials[i];
    float r = block_reduce_sum(acc);
    if (threadIdx.x == 0) out[0] = r * invB;
}

extern "C" void kernel_launch(void* const* d_in, const int* in_sizes, int n_in,
                              void* d_out, int out_size, void* d_ws, size_t ws_size,
                              hipStream_t stream) {
    const float* p       = (const float*)d_in[0];
    const int*   classes = (const int*)d_in[1];
    float*       out     = (float*)d_out;
    float*       ws      = (float*)d_ws;

    const long long N = (long long)in_sizes[0];   // B*C
    const int B = in_sizes[1];
    const int C = (int)(N / B);
    const int n4 = (int)(N / 4);                  // N divisible by 4

    float* part_main = ws;                        // GRID_MAIN floats
    float* part_fix  = ws + GRID_MAIN;            // GRID_FIX floats (contiguous)

    focal_main<<<GRID_MAIN, BLOCK, 0, stream>>>((const float4*)p, part_main, n4);
    focal_fix <<<GRID_FIX,  BLOCK, 0, stream>>>(p, classes, part_fix, B, C);
    focal_final<<<1, BLOCK, 0, stream>>>(ws, GRID_MAIN + GRID_FIX, out, 1.0f / (float)B);
}

// Round 3
// 53.037 us; speedup vs baseline: 1.0451x; 1.0451x over previous
//
#include <hip/hip_runtime.h>
#include <hip/hip_bf16.h>

static constexpr int BLOCK     = 256;
static constexpr int GRID_MAIN = 2048;

typedef float f32x4 __attribute__((ext_vector_type(4)));

__device__ __forceinline__ float patch_nan(float x) {
    return (x != x) ? 1e-6f : x;
}

// non-target term: -(1-alpha) * p^2 * ln(1-p)   (alpha = 0.25)
__device__ __forceinline__ float neg_term(float x) {
    return -0.75f * x * x * __logf(1.0f - x);
}

// target term: -alpha * (1-p)^2 * ln(p)
__device__ __forceinline__ float pos_term(float x) {
    float om = 1.0f - x;
    return -0.25f * om * om * __logf(x);
}

// Block-wide sum; result valid in thread 0 only.
__device__ __forceinline__ float block_reduce_sum(float v) {
    #pragma unroll
    for (int off = 32; off > 0; off >>= 1)
        v += __shfl_down(v, off, 64);
    __shared__ float smem[BLOCK / 64];
    const int lane = threadIdx.x & 63;
    const int wid  = threadIdx.x >> 6;
    if (lane == 0) smem[wid] = v;
    __syncthreads();
    float r = 0.0f;
    if (threadIdx.x == 0) {
        #pragma unroll
        for (int i = 0; i < BLOCK / 64; ++i) r += smem[i];
    }
    return r;
}

// Fused pass: neg term for every element (coalesced float4 nontemporal
// stream) + inline target-class correction (adds pos - neg at the one
// target column per row). shiftC4 = log2(C/4); C is a power of two (2048).
__global__ void __launch_bounds__(BLOCK)
focal_fused(const f32x4* __restrict__ p4, const int* __restrict__ classes,
            float* __restrict__ partials, int n4, int shiftC4) {
    float acc = 0.0f;
    const int maskC4  = (1 << shiftC4) - 1;
    const int stride  = gridDim.x * blockDim.x;
    for (int i = blockIdx.x * blockDim.x + threadIdx.x; i < n4; i += stride) {
        f32x4 v = __builtin_nontemporal_load(&p4[i]);
        float x0 = patch_nan(v.x), x1 = patch_nan(v.y);
        float x2 = patch_nan(v.z), x3 = patch_nan(v.w);
        acc += neg_term(x0);
        acc += neg_term(x1);
        acc += neg_term(x2);
        acc += neg_term(x3);
        const int row     = i >> shiftC4;
        const int colbase = (i & maskC4) << 2;
        const unsigned d  = (unsigned)(classes[row] - colbase);
        if (d < 4u) {  // target column falls inside this float4
            float x = (d == 0) ? x0 : (d == 1) ? x1 : (d == 2) ? x2 : x3;
            acc += pos_term(x) - neg_term(x);
        }
    }
    float r = block_reduce_sum(acc);
    if (threadIdx.x == 0) partials[blockIdx.x] = r;
}

// Deterministic final reduction of the 2048 partials, scale by 1/B.
__global__ void __launch_bounds__(BLOCK)
focal_final(const float* __restrict__ partials, int n,
            float* __restrict__ out, float invB) {
    float acc = 0.0f;
    for (int i = threadIdx.x; i < n; i += blockDim.x) acc += partials[i];
    float r = block_reduce_sum(acc);
    if (threadIdx.x == 0) out[0] = r * invB;
}

extern "C" void kernel_launch(void* const* d_in, const int* in_sizes, int n_in,
                              void* d_out, int out_size, void* d_ws, size_t ws_size,
                              hipStream_t stream) {
    const float* p       = (const float*)d_in[0];
    const int*   classes = (const int*)d_in[1];
    float*       out     = (float*)d_out;
    float*       ws      = (float*)d_ws;

    const long long N = (long long)in_sizes[0];   // B*C
    const int B  = in_sizes[1];
    const int C  = (int)(N / B);                  // 2048 (power of two)
    const int n4 = (int)(N / 4);
    const int c4 = C / 4;

    int shiftC4 = 0;
    while ((1 << shiftC4) < c4) ++shiftC4;        // log2(C/4) = 9

    focal_fused<<<GRID_MAIN, BLOCK, 0, stream>>>((const f32x4*)p, classes,
                                                 ws, n4, shiftC4);
    focal_final<<<1, BLOCK, 0, stream>>>(ws, GRID_MAIN, out, 1.0f / (float)B);
}